// Round 1
// baseline (322.828 us; speedup 1.0000x reference)
//
#include <hip/hip_runtime.h>
#include <math.h>

constexpr int B_ = 128;
constexpr int N_ = 512;
constexpr int K_ = 510;   // number of diagonals = N-2

// Kernel 1: per (batch, row-slice) partial sums of x and x^2 per diagonal k.
// Rows are read coalesced; element (p,c), c>p, belongs to diagonal k=c-p-1.
// Within a row all k are distinct, so LDS atomics rarely collide.
__global__ __launch_bounds__(512) void diag_partial_kernel(
    const float* __restrict__ in, float* __restrict__ ws, int split) {
  __shared__ float S[N_];
  __shared__ float Q[N_];
  const int b = blockIdx.x / split;
  const int s = blockIdx.x % split;
  const int t = threadIdx.x;
  S[t] = 0.0f;
  Q[t] = 0.0f;
  __syncthreads();
  const float* base = in + (size_t)b * N_ * N_;
  // interleaved rows for load balance (row p has 511-p elements)
  for (int p = s; p < N_ - 1; p += split) {
    if (t > p) {
      float x = base[p * N_ + t];
      int k = t - p - 1;
      atomicAdd(&S[k], x);         // ds_add_f32, consecutive lanes -> consecutive banks
      atomicAdd(&Q[k], x * x);
    }
  }
  __syncthreads();
  float* w = ws + (size_t)blockIdx.x * (2 * N_);  // blockIdx.x == b*split+s
  w[t] = S[t];
  w[t + N_] = Q[t];
}

// Kernel 2: combine partials, compute scaled = sqrt(var)*len/5 per k,
// reduce mean over k, write both tuple outputs.
__global__ __launch_bounds__(512) void finalize_kernel(
    const float* __restrict__ ws, float* __restrict__ out, int split) {
  __shared__ float red[8];
  const int b = blockIdx.x;
  const int t = threadIdx.x;
  float Ssum = 0.0f, Qsum = 0.0f;
  for (int s = 0; s < split; ++s) {
    const float* w = ws + (size_t)(b * split + s) * (2 * N_);
    Ssum += w[t];
    Qsum += w[t + N_];
  }
  float scaled = 0.0f;
  if (t < K_) {
    float len = (float)(N_ - 1 - t);
    float mean = Ssum / len;
    float var = (Qsum - Ssum * mean) / (len - 1.0f);
    var = fmaxf(var, 0.0f);        // guard tiny negative from rounding
    scaled = sqrtf(var) * len * 0.2f;
  }
  // wave-64 reduction
  for (int off = 32; off > 0; off >>= 1)
    scaled += __shfl_down(scaled, off, 64);
  const int wid = t >> 6;
  if ((t & 63) == 0) red[wid] = scaled;
  __syncthreads();
  if (t == 0) {
    float tot = 0.0f;
    for (int i = 0; i < 8; ++i) tot += red[i];
    float loss = tot / (float)K_;
    out[b] = loss;        // output 0: loss
    out[B_ + b] = loss;   // output 1: stop_gradient(loss) == loss
  }
}

extern "C" void kernel_launch(void* const* d_in, const int* in_sizes, int n_in,
                              void* d_out, int out_size, void* d_ws, size_t ws_size,
                              hipStream_t stream) {
  const float* in = (const float*)d_in[0];
  float* out = (float*)d_out;
  float* ws = (float*)d_ws;
  // pick largest row-split whose partial buffer fits the workspace
  int split = 8;
  while (split > 1 &&
         (size_t)B_ * split * 2 * N_ * sizeof(float) > ws_size)
    split >>= 1;
  diag_partial_kernel<<<B_ * split, 512, 0, stream>>>(in, ws, split);
  finalize_kernel<<<B_, 512, 0, stream>>>(ws, out, split);
}

// Round 2
// 196.781 us; speedup vs baseline: 1.6405x; 1.6405x over previous
//
#include <hip/hip_runtime.h>
#include <math.h>

constexpr int B_ = 128;
constexpr int N_ = 512;
constexpr int K_ = 510;   // number of diagonals = N-2

// Kernel 1: thread k owns diagonal k; iterate rows p (interleaved mod split).
// For fixed p, lane k reads in[b, p, p+1+k] -> consecutive lanes hit
// consecutive addresses (coalesced). Accumulate S=sum(x), Q=sum(x^2) in
// REGISTERS -- no LDS, no atomics (round 1's LDS float atomicAdd compiled to
// a CAS loop and was 100% of the stall).
__global__ __launch_bounds__(512) void diag_partial_kernel(
    const float* __restrict__ in, float* __restrict__ ws, int split) {
  const int b = blockIdx.x / split;
  const int s = blockIdx.x % split;
  const int k = threadIdx.x;
  const float* base = in + (size_t)b * N_ * N_;
  float S = 0.0f, Q = 0.0f;
  if (k < K_) {
    const int limit = N_ - 1 - k;  // p in [0, limit)
    // element (p, p+1+k) = base[p*(N+1) + 1 + k]
    const float* ptr = base + (size_t)s * (N_ + 1) + 1 + k;
    for (int p = s; p < limit; p += split) {
      float x = *ptr;
      S += x;
      Q = fmaf(x, x, Q);
      ptr += (size_t)split * (N_ + 1);
    }
  }
  float* w = ws + (size_t)blockIdx.x * (2 * N_);  // blockIdx.x == b*split+s
  w[k] = S;
  w[k + N_] = Q;
}

// Kernel 2: combine partials, compute scaled = sqrt(var)*len/5 per k,
// reduce mean over k, write both tuple outputs.
__global__ __launch_bounds__(512) void finalize_kernel(
    const float* __restrict__ ws, float* __restrict__ out, int split) {
  __shared__ float red[8];
  const int b = blockIdx.x;
  const int t = threadIdx.x;
  float Ssum = 0.0f, Qsum = 0.0f;
  for (int s = 0; s < split; ++s) {
    const float* w = ws + (size_t)(b * split + s) * (2 * N_);
    Ssum += w[t];
    Qsum += w[t + N_];
  }
  float scaled = 0.0f;
  if (t < K_) {
    float len = (float)(N_ - 1 - t);
    float mean = Ssum / len;
    float var = (Qsum - Ssum * mean) / (len - 1.0f);
    var = fmaxf(var, 0.0f);        // guard tiny negative from rounding
    scaled = sqrtf(var) * len * 0.2f;
  }
  // wave-64 reduction
  for (int off = 32; off > 0; off >>= 1)
    scaled += __shfl_down(scaled, off, 64);
  const int wid = t >> 6;
  if ((t & 63) == 0) red[wid] = scaled;
  __syncthreads();
  if (t == 0) {
    float tot = 0.0f;
    for (int i = 0; i < 8; ++i) tot += red[i];
    float loss = tot / (float)K_;
    out[b] = loss;        // output 0: loss
    out[B_ + b] = loss;   // output 1: stop_gradient(loss) == loss
  }
}

extern "C" void kernel_launch(void* const* d_in, const int* in_sizes, int n_in,
                              void* d_out, int out_size, void* d_ws, size_t ws_size,
                              hipStream_t stream) {
  const float* in = (const float*)d_in[0];
  float* out = (float*)d_out;
  float* ws = (float*)d_ws;
  // pick largest row-split whose partial buffer fits the workspace
  int split = 8;
  while (split > 1 &&
         (size_t)B_ * split * 2 * N_ * sizeof(float) > ws_size)
    split >>= 1;
  diag_partial_kernel<<<B_ * split, 512, 0, stream>>>(in, ws, split);
  finalize_kernel<<<B_, 512, 0, stream>>>(ws, out, split);
}

// Round 3
// 182.058 us; speedup vs baseline: 1.7732x; 1.0809x over previous
//
#include <hip/hip_runtime.h>
#include <math.h>

constexpr int B_ = 128;
constexpr int N_ = 512;
constexpr int K_ = 510;   // number of diagonals = N-2

// Kernel 1: thread k owns diagonal k; iterate rows p (interleaved mod split).
// For fixed p, lane k reads in[b, p, p+1+k] -> consecutive lanes hit
// consecutive addresses (coalesced). Accumulate S=sum(x), Q=sum(x^2) in
// registers. 4-row manual unroll keeps 4 independent loads in flight per
// wave (R2's VGPR=4 build had only 1 -> latency-bound).
__global__ __launch_bounds__(512) void diag_partial_kernel(
    const float* __restrict__ in, float* __restrict__ ws, int split) {
  const int b = blockIdx.x / split;
  const int s = blockIdx.x % split;
  const int k = threadIdx.x;
  const float* base = in + (size_t)b * N_ * N_;
  float S0 = 0.f, Q0 = 0.f, S1 = 0.f, Q1 = 0.f;
  float S2 = 0.f, Q2 = 0.f, S3 = 0.f, Q3 = 0.f;
  if (k < K_) {
    const int limit = N_ - 1 - k;          // p in [0, limit)
    const size_t step = (size_t)split * (N_ + 1);
    const float* ptr = base + (size_t)s * (N_ + 1) + 1 + k;
    int p = s;
    for (; p + 3 * split < limit; p += 4 * split) {
      float x0 = ptr[0];
      float x1 = ptr[step];
      float x2 = ptr[2 * step];
      float x3 = ptr[3 * step];
      S0 += x0; Q0 = fmaf(x0, x0, Q0);
      S1 += x1; Q1 = fmaf(x1, x1, Q1);
      S2 += x2; Q2 = fmaf(x2, x2, Q2);
      S3 += x3; Q3 = fmaf(x3, x3, Q3);
      ptr += 4 * step;
    }
    for (; p < limit; p += split) {
      float x = *ptr;
      S0 += x; Q0 = fmaf(x, x, Q0);
      ptr += step;
    }
  }
  float S = (S0 + S1) + (S2 + S3);
  float Q = (Q0 + Q1) + (Q2 + Q3);
  float* w = ws + (size_t)blockIdx.x * (2 * N_);  // blockIdx.x == b*split+s
  w[k] = S;
  w[k + N_] = Q;
}

// Kernel 2: combine partials, compute scaled = sqrt(var)*len/5 per k,
// reduce mean over k, write both tuple outputs.
__global__ __launch_bounds__(512) void finalize_kernel(
    const float* __restrict__ ws, float* __restrict__ out, int split) {
  __shared__ float red[8];
  const int b = blockIdx.x;
  const int t = threadIdx.x;
  float Ssum = 0.0f, Qsum = 0.0f;
  for (int s = 0; s < split; ++s) {
    const float* w = ws + (size_t)(b * split + s) * (2 * N_);
    Ssum += w[t];
    Qsum += w[t + N_];
  }
  float scaled = 0.0f;
  if (t < K_) {
    float len = (float)(N_ - 1 - t);
    float mean = Ssum / len;
    float var = (Qsum - Ssum * mean) / (len - 1.0f);
    var = fmaxf(var, 0.0f);        // guard tiny negative from rounding
    scaled = sqrtf(var) * len * 0.2f;
  }
  // wave-64 reduction
  for (int off = 32; off > 0; off >>= 1)
    scaled += __shfl_down(scaled, off, 64);
  const int wid = t >> 6;
  if ((t & 63) == 0) red[wid] = scaled;
  __syncthreads();
  if (t == 0) {
    float tot = 0.0f;
    for (int i = 0; i < 8; ++i) tot += red[i];
    float loss = tot / (float)K_;
    out[b] = loss;        // output 0: loss
    out[B_ + b] = loss;   // output 1: stop_gradient(loss) == loss
  }
}

extern "C" void kernel_launch(void* const* d_in, const int* in_sizes, int n_in,
                              void* d_out, int out_size, void* d_ws, size_t ws_size,
                              hipStream_t stream) {
  const float* in = (const float*)d_in[0];
  float* out = (float*)d_out;
  float* ws = (float*)d_ws;
  // split=16: 2048 blocks (8/CU) keeps CUs fed through the triangular tail.
  int split = 16;
  while (split > 1 &&
         (size_t)B_ * split * 2 * N_ * sizeof(float) > ws_size)
    split >>= 1;
  diag_partial_kernel<<<B_ * split, 512, 0, stream>>>(in, ws, split);
  finalize_kernel<<<B_, 512, 0, stream>>>(ws, out, split);
}

// Round 4
// 181.527 us; speedup vs baseline: 1.7784x; 1.0029x over previous
//
#include <hip/hip_runtime.h>
#include <math.h>

constexpr int B_ = 128;
constexpr int N_ = 512;
constexpr int K_ = 510;   // number of diagonals = N-2

// Kernel 1: thread t owns TWO diagonals: k_a = t (length 511-t) and
// k_b = 511-t (length t). Per-lane work = 511 rows for EVERY thread ->
// perfectly uniform across lanes/waves/SIMDs/blocks (round 3's k=t mapping
// put all long diagonals on SIMD0 -> ~2-3x critical-path inflation).
// Both streams are lane-contiguous (one coalesced 256B segment per wave).
// Element (p, c): stream a: c = p+1+t; stream b: c = p+512-t (valid p < t).
__global__ __launch_bounds__(256) void diag_partial_kernel(
    const float* __restrict__ in, float* __restrict__ ws, int split) {
  const int b = blockIdx.x / split;
  const int s = blockIdx.x % split;
  const int t = threadIdx.x;            // t in [0,256)
  const float* base = in + (size_t)b * N_ * N_;
  const int la = (N_ - 1) - t;          // rows of diag k_a = t
  const int lb = t;                     // rows of diag k_b = 511-t
  const size_t step = (size_t)split * (N_ + 1);
  const float* pa = base + (size_t)s * (N_ + 1) + 1 + t;
  const float* pb = base + (size_t)s * (N_ + 1) + (N_ - t);
  float Sa0 = 0.f, Qa0 = 0.f, Sa1 = 0.f, Qa1 = 0.f;
  float Sb0 = 0.f, Qb0 = 0.f, Sb1 = 0.f, Qb1 = 0.f;
  int p = s;
  // la > lb for all t in [0,256), so la bounds the fused loop.
  for (; p + 3 * split < la; p += 4 * split) {
    float a0 = pa[0];
    float a1 = pa[step];
    float a2 = pa[2 * step];
    float a3 = pa[3 * step];
    float b0 = 0.f, b1 = 0.f, b2 = 0.f, b3 = 0.f;
    if (p < lb)             b0 = pb[0];
    if (p + split < lb)     b1 = pb[step];
    if (p + 2 * split < lb) b2 = pb[2 * step];
    if (p + 3 * split < lb) b3 = pb[3 * step];
    Sa0 += a0; Qa0 = fmaf(a0, a0, Qa0);
    Sa1 += a1; Qa1 = fmaf(a1, a1, Qa1);
    Sa0 += a2; Qa0 = fmaf(a2, a2, Qa0);
    Sa1 += a3; Qa1 = fmaf(a3, a3, Qa1);
    Sb0 += b0; Qb0 = fmaf(b0, b0, Qb0);
    Sb1 += b1; Qb1 = fmaf(b1, b1, Qb1);
    Sb0 += b2; Qb0 = fmaf(b2, b2, Qb0);
    Sb1 += b3; Qb1 = fmaf(b3, b3, Qb1);
    pa += 4 * step;
    pb += 4 * step;
  }
  for (; p < la; p += split) {
    float a0 = pa[0];
    Sa0 += a0; Qa0 = fmaf(a0, a0, Qa0);
    if (p < lb) {
      float b0 = pb[0];
      Sb0 += b0; Qb0 = fmaf(b0, b0, Qb0);
    }
    pa += step;
    pb += step;
  }
  float* w = ws + (size_t)blockIdx.x * (2 * N_);  // blockIdx.x == b*split+s
  // thread t writes k=t and k=511-t (disjoint: [0,256) vs [256,512))
  w[t] = Sa0 + Sa1;
  w[t + N_] = Qa0 + Qa1;
  w[(N_ - 1) - t] = Sb0 + Sb1;
  w[(N_ - 1) - t + N_] = Qb0 + Qb1;
}

// Kernel 2: combine partials, compute scaled = sqrt(var)*len/5 per k,
// reduce mean over k, write both tuple outputs.
__global__ __launch_bounds__(512) void finalize_kernel(
    const float* __restrict__ ws, float* __restrict__ out, int split) {
  __shared__ float red[8];
  const int b = blockIdx.x;
  const int t = threadIdx.x;
  float Ssum = 0.0f, Qsum = 0.0f;
  for (int s = 0; s < split; ++s) {
    const float* w = ws + (size_t)(b * split + s) * (2 * N_);
    Ssum += w[t];
    Qsum += w[t + N_];
  }
  float scaled = 0.0f;
  if (t < K_) {
    float len = (float)(N_ - 1 - t);
    float mean = Ssum / len;
    float var = (Qsum - Ssum * mean) / (len - 1.0f);
    var = fmaxf(var, 0.0f);        // guard tiny negative from rounding
    scaled = sqrtf(var) * len * 0.2f;
  }
  // wave-64 reduction
  for (int off = 32; off > 0; off >>= 1)
    scaled += __shfl_down(scaled, off, 64);
  const int wid = t >> 6;
  if ((t & 63) == 0) red[wid] = scaled;
  __syncthreads();
  if (t == 0) {
    float tot = 0.0f;
    for (int i = 0; i < 8; ++i) tot += red[i];
    float loss = tot / (float)K_;
    out[b] = loss;        // output 0: loss
    out[B_ + b] = loss;   // output 1: stop_gradient(loss) == loss
  }
}

extern "C" void kernel_launch(void* const* d_in, const int* in_sizes, int n_in,
                              void* d_out, int out_size, void* d_ws, size_t ws_size,
                              hipStream_t stream) {
  const float* in = (const float*)d_in[0];
  float* out = (float*)d_out;
  float* ws = (float*)d_ws;
  // split=16: 2048 blocks of 256 threads -> 8 blocks/CU, 32 waves/CU.
  int split = 16;
  while (split > 1 &&
         (size_t)B_ * split * 2 * N_ * sizeof(float) > ws_size)
    split >>= 1;
  diag_partial_kernel<<<B_ * split, 256, 0, stream>>>(in, ws, split);
  finalize_kernel<<<B_, 512, 0, stream>>>(ws, out, split);
}

// Round 5
// 178.854 us; speedup vs baseline: 1.8050x; 1.0149x over previous
//
#include <hip/hip_runtime.h>
#include <math.h>

constexpr int B_ = 128;
constexpr int N_ = 512;
constexpr int K_ = 510;     // number of diagonals = N-2
constexpr int SPLIT = 16;   // compile-time: lets finalize's s-loop fully unroll

// Kernel 1: thread t owns TWO diagonals: k_a = t (length 511-t) and
// k_b = 511-t (length t). Per-lane work = 511 rows for EVERY thread ->
// uniform across lanes/waves/SIMDs/blocks. Both streams lane-contiguous
// (one coalesced 256B segment per wave). Register-only accumulation.
__global__ __launch_bounds__(256) void diag_partial_kernel(
    const float* __restrict__ in, float* __restrict__ ws) {
  const int b = blockIdx.x / SPLIT;
  const int s = blockIdx.x % SPLIT;
  const int t = threadIdx.x;            // t in [0,256)
  const float* base = in + (size_t)b * N_ * N_;
  const int la = (N_ - 1) - t;          // rows of diag k_a = t
  const int lb = t;                     // rows of diag k_b = 511-t
  constexpr size_t step = (size_t)SPLIT * (N_ + 1);
  const float* pa = base + (size_t)s * (N_ + 1) + 1 + t;
  const float* pb = base + (size_t)s * (N_ + 1) + (N_ - t);
  float Sa0 = 0.f, Qa0 = 0.f, Sa1 = 0.f, Qa1 = 0.f;
  float Sb0 = 0.f, Qb0 = 0.f, Sb1 = 0.f, Qb1 = 0.f;
  int p = s;
  // la > lb for all t in [0,256), so la bounds the fused loop.
  for (; p + 3 * SPLIT < la; p += 4 * SPLIT) {
    float a0 = pa[0];
    float a1 = pa[step];
    float a2 = pa[2 * step];
    float a3 = pa[3 * step];
    float b0 = 0.f, b1 = 0.f, b2 = 0.f, b3 = 0.f;
    if (p < lb)             b0 = pb[0];
    if (p + SPLIT < lb)     b1 = pb[step];
    if (p + 2 * SPLIT < lb) b2 = pb[2 * step];
    if (p + 3 * SPLIT < lb) b3 = pb[3 * step];
    Sa0 += a0; Qa0 = fmaf(a0, a0, Qa0);
    Sa1 += a1; Qa1 = fmaf(a1, a1, Qa1);
    Sa0 += a2; Qa0 = fmaf(a2, a2, Qa0);
    Sa1 += a3; Qa1 = fmaf(a3, a3, Qa1);
    Sb0 += b0; Qb0 = fmaf(b0, b0, Qb0);
    Sb1 += b1; Qb1 = fmaf(b1, b1, Qb1);
    Sb0 += b2; Qb0 = fmaf(b2, b2, Qb0);
    Sb1 += b3; Qb1 = fmaf(b3, b3, Qb1);
    pa += 4 * step;
    pb += 4 * step;
  }
  for (; p < la; p += SPLIT) {
    float a0 = pa[0];
    Sa0 += a0; Qa0 = fmaf(a0, a0, Qa0);
    if (p < lb) {
      float b0 = pb[0];
      Sb0 += b0; Qb0 = fmaf(b0, b0, Qb0);
    }
    pa += step;
    pb += step;
  }
  float* w = ws + (size_t)blockIdx.x * (2 * N_);  // blockIdx.x == b*SPLIT+s
  // thread t writes k=t and k=511-t (disjoint: [0,256) vs [256,512))
  w[t] = Sa0 + Sa1;
  w[t + N_] = Qa0 + Qa1;
  w[(N_ - 1) - t] = Sb0 + Sb1;
  w[(N_ - 1) - t + N_] = Qb0 + Qb1;
}

// Kernel 2: combine partials (fully-unrolled constant-trip loop -> 32
// independent loads in flight; runtime-split version serialized them and
// was ~20us at 128 blocks), compute scaled = sqrt(var)*len/5 per k,
// reduce mean over k, write both tuple outputs.
__global__ __launch_bounds__(512) void finalize_kernel(
    const float* __restrict__ ws, float* __restrict__ out) {
  __shared__ float red[8];
  const int b = blockIdx.x;
  const int t = threadIdx.x;
  float Ssum = 0.0f, Qsum = 0.0f;
#pragma unroll
  for (int s = 0; s < SPLIT; ++s) {
    const float* w = ws + (size_t)(b * SPLIT + s) * (2 * N_);
    Ssum += w[t];
    Qsum += w[t + N_];
  }
  float scaled = 0.0f;
  if (t < K_) {
    float len = (float)(N_ - 1 - t);
    float mean = Ssum / len;
    float var = (Qsum - Ssum * mean) / (len - 1.0f);
    var = fmaxf(var, 0.0f);        // guard tiny negative from rounding
    scaled = sqrtf(var) * len * 0.2f;
  }
  // wave-64 reduction
  for (int off = 32; off > 0; off >>= 1)
    scaled += __shfl_down(scaled, off, 64);
  const int wid = t >> 6;
  if ((t & 63) == 0) red[wid] = scaled;
  __syncthreads();
  if (t == 0) {
    float tot = 0.0f;
    for (int i = 0; i < 8; ++i) tot += red[i];
    float loss = tot / (float)K_;
    out[b] = loss;        // output 0: loss
    out[B_ + b] = loss;   // output 1: stop_gradient(loss) == loss
  }
}

extern "C" void kernel_launch(void* const* d_in, const int* in_sizes, int n_in,
                              void* d_out, int out_size, void* d_ws, size_t ws_size,
                              hipStream_t stream) {
  const float* in = (const float*)d_in[0];
  float* out = (float*)d_out;
  float* ws = (float*)d_ws;
  // 2048 blocks of 256 threads -> 8 blocks/CU, 32 waves/CU. ws use: 8 MB.
  diag_partial_kernel<<<B_ * SPLIT, 256, 0, stream>>>(in, ws);
  finalize_kernel<<<B_, 512, 0, stream>>>(ws, out);
}